// Round 2
// baseline (464.402 us; speedup 1.0000x reference)
//
#include <hip/hip_runtime.h>

typedef unsigned short u16;
typedef unsigned int   u32;
typedef short s16x8 __attribute__((ext_vector_type(8)));
typedef float f32x4 __attribute__((ext_vector_type(4)));

#define MFMA16(A,B,C) __builtin_amdgcn_mfma_f32_16x16x32_bf16((A),(B),(C),0,0,0)
#define BAR() asm volatile("s_barrier" ::: "memory")

#define B_   32
#define S_   257
#define E_   1024
#define H_   16
#define D_   64
#define I_   4096
#define M_   (B_*S_)   // 8224

__device__ __forceinline__ u16 f2bf(float f) {
    u32 u = __float_as_uint(f);
    u32 r = u + 0x7fffu + ((u >> 16) & 1u);
    return (u16)(r >> 16);
}
__device__ __forceinline__ float bf2f(u16 b) {
    return __uint_as_float(((u32)b) << 16);
}

__device__ __forceinline__ void gload16(const void* g, void* l) {
    __builtin_amdgcn_global_load_lds(
        (const __attribute__((address_space(1))) u32*)g,
        (__attribute__((address_space(3))) u32*)l, 16, 0, 0);
}

// ---------------- weight fp32 -> bf16 convert (12M elems) ----------------
__global__ __launch_bounds__(256)
void convert_w_kernel(const float* __restrict__ qw, const float* __restrict__ kw,
                      const float* __restrict__ vw, const float* __restrict__ ow,
                      const float* __restrict__ f1, const float* __restrict__ f2,
                      u16* __restrict__ dst)
{
    const int total4 = (12 * 1048576) / 4;
    for (int i = blockIdx.x * 256 + threadIdx.x; i < total4; i += gridDim.x * 256) {
        int e = i * 4;
        int seg = e >> 20;
        const float* srcp; int off;
        if (seg < 4)      { srcp = (seg == 0 ? qw : seg == 1 ? kw : seg == 2 ? vw : ow); off = e & 1048575; }
        else if (seg < 8) { srcp = f1; off = e - 4 * 1048576; }
        else              { srcp = f2; off = e - 8 * 1048576; }
        float4 v = *(const float4*)(srcp + off);
        ushort4 o;
        o.x = f2bf(v.x); o.y = f2bf(v.y); o.z = f2bf(v.z); o.w = f2bf(v.w);
        *(ushort4*)(dst + e) = o;
    }
}

// ---------------- combined mask table: msum[b][sq][272] bf16 ----------------
__global__ __launch_bounds__(256)
void mask_combine_kernel(const float* __restrict__ am, const float* __restrict__ cm,
                         u16* __restrict__ msum)
{
    const int total = B_ * S_ * 272;
    for (int i = blockIdx.x * 256 + threadIdx.x; i < total; i += gridDim.x * 256) {
        int skv = i % 272;
        int rem = i / 272;
        int sq  = rem % S_;
        int b   = rem / S_;
        float v;
        if (skv < S_) {
            size_t o = ((size_t)b * S_ + sq) * S_ + skv;
            v = am[o] + cm[o];
        } else v = -1e30f;
        msum[i] = f2bf(v);
    }
}

// ---------------- LayerNorm row kernel ----------------
__global__ __launch_bounds__(256)
void ln_kernel(const float* __restrict__ src, const float* __restrict__ gam,
               const float* __restrict__ bet, u16* __restrict__ dst)
{
    int row = blockIdx.x;
    const float4* p = (const float4*)(src + (size_t)row * E_);
    float4 x = p[threadIdx.x];
    float s  = x.x + x.y + x.z + x.w;
    float s2 = x.x * x.x + x.y * x.y + x.z * x.z + x.w * x.w;
#pragma unroll
    for (int xm = 1; xm < 64; xm <<= 1) {
        s  += __shfl_xor(s,  xm, 64);
        s2 += __shfl_xor(s2, xm, 64);
    }
    __shared__ float red[8];
    int wv = threadIdx.x >> 6;
    if ((threadIdx.x & 63) == 0) { red[wv] = s; red[4 + wv] = s2; }
    __syncthreads();
    s  = red[0] + red[1] + red[2] + red[3];
    s2 = red[4] + red[5] + red[6] + red[7];
    float mu  = s * (1.0f / 1024.0f);
    float var = s2 * (1.0f / 1024.0f) - mu * mu;
    float rs  = rsqrtf(var + 1e-5f);
    float4 g  = ((const float4*)gam)[threadIdx.x];
    float4 be = ((const float4*)bet)[threadIdx.x];
    ushort4 o;
    o.x = f2bf((x.x - mu) * rs * g.x + be.x);
    o.y = f2bf((x.y - mu) * rs * g.y + be.y);
    o.z = f2bf((x.z - mu) * rs * g.z + be.z);
    o.w = f2bf((x.w - mu) * rs * g.w + be.w);
    ((ushort4*)dst)[(size_t)row * 256 + threadIdx.x] = o;
}

// ---------------- 256x256 8-phase NT GEMM (BK=32, 8 waves, 64KB LDS) -------
// C[m][n] = sum_k A[m][k]*B[n][k]
// MODE 0: fused QKV -> bf16 [B,H,S,D] (q scaled by 1/8 incl. bias)
// MODE 1: f32 out = acc + bias + res
// MODE 2: bf16 out = gelu_tanh(acc + bias)
// LDS swizzle: phys_byte = logical_byte ^ (((logical_byte>>7)&3)<<4)
//   (involution; write side pre-swizzles the per-lane GLOBAL source since
//    global_load_lds writes linearly: uniform base + lane*16)
template<int MODE>
__global__ __launch_bounds__(512, 2)
void gemm8(const u16* __restrict__ A,
           const u16* __restrict__ Bq, const u16* __restrict__ Bk, const u16* __restrict__ Bv,
           const float* __restrict__ biasq, const float* __restrict__ biask, const float* __restrict__ biasvv,
           const float* __restrict__ res, float* __restrict__ outF,
           u16* __restrict__ outBq, u16* __restrict__ outBk, u16* __restrict__ outBv,
           int M, int N, int K)
{
    __shared__ u16 lds[8][4096];   // [buf*4 + mat*2 + half][128 rows * 32 cols] = 64 KB
    const int tid  = threadIdx.x;
    const int lane = tid & 63, w = tid >> 6;
    const int lr = lane & 15, lg = lane >> 4;
    const int wm = w >> 2, wn = w & 3;          // 2 x 4 wave grid
    const int mt = blockIdx.y;

    const u16* Bm = Bq; const float* bias = biasq; u16* outB = outBq;
    float scl = 1.0f; int nt = blockIdx.x;
    if (MODE == 0) {
        int mat = nt >> 2; nt &= 3;
        if (mat == 1)      { Bm = Bk; bias = biask; outB = outBk; }
        else if (mat == 2) { Bm = Bv; bias = biasvv; outB = outBv; }
        if (mat == 0) scl = 0.125f;             // D^-0.5
    }
    const int m0 = mt * 256, n0 = nt * 256;
    const int NT = K >> 5;

    // stage one 128x32 half (8KB): 1 gload_lds per thread
    auto STAGE = [&](const u16* g, int grow0, int rowmax, int kt, int mat, int h) {
        char* dst = (char*)&lds[((kt & 1) << 2) + (mat << 1) + h][0] + w * 1024; // wave-uniform
        int p = (w * 64 + lane) << 4;                 // this lane's dest byte
        int l = p ^ (((p >> 7) & 3) << 4);            // inverse swizzle -> logical
        int row = l >> 6, cc = (l >> 4) & 3;
        int gr = grow0 + row; if (gr > rowmax) gr = rowmax;
        gload16(g + (size_t)gr * K + (kt << 5) + cc * 8, dst);
    };
    const int swv = ((lr >> 1) & 3) << 4;             // per-thread read swizzle
    auto LDA = [&](int kt, int mh, int mf) -> s16x8 {
        const char* base = (const char*)&lds[((kt & 1) << 2) + wm][0];
        return *(const s16x8*)(base + (mh * 64 + mf * 16 + lr) * 64 + ((lg * 16) ^ swv));
    };
    auto LDB = [&](int kt, int nh, int nf) -> s16x8 {
        const char* base = (const char*)&lds[((kt & 1) << 2) + 2 + (wn >> 1)][0];
        return *(const s16x8*)(base + ((wn & 1) * 64 + nh * 32 + nf * 16 + lr) * 64 + ((lg * 16) ^ swv));
    };

    f32x4 acc[8][4];
#pragma unroll
    for (int i = 0; i < 8; ++i)
#pragma unroll
        for (int j = 0; j < 4; ++j) { f32x4 z = {0.f, 0.f, 0.f, 0.f}; acc[i][j] = z; }

    // prologue: tile0 fully + tile1.A0 in flight
    STAGE(A,  m0,       M - 1, 0, 0, 0);
    STAGE(A,  m0 + 128, M - 1, 0, 0, 1);
    STAGE(Bm, n0,       N - 1, 0, 1, 0);
    STAGE(Bm, n0 + 128, N - 1, 0, 1, 1);
    if (NT > 1) {
        STAGE(A, m0, M - 1, 1, 0, 0);
        asm volatile("s_waitcnt vmcnt(1)" ::: "memory");
    } else {
        asm volatile("s_waitcnt vmcnt(0)" ::: "memory");
    }
    BAR();

    s16x8 aq[4], b0q[2], b1q[2];
    for (int kt = 0; kt < NT; ++kt) {
        // ---- phase 0: quadrant (mh=0, nh=0) ----
#pragma unroll
        for (int mf = 0; mf < 4; ++mf) aq[mf] = LDA(kt, 0, mf);
#pragma unroll
        for (int nf = 0; nf < 2; ++nf) b0q[nf] = LDB(kt, 0, nf);
        if (kt + 1 < NT) {
            STAGE(A,  m0 + 128, M - 1, kt + 1, 0, 1);
            STAGE(Bm, n0,       N - 1, kt + 1, 1, 0);
        }
        BAR();
        __builtin_amdgcn_s_setprio(1);
#pragma unroll
        for (int mf = 0; mf < 4; ++mf)
#pragma unroll
            for (int nf = 0; nf < 2; ++nf)
                acc[mf][nf] = MFMA16(aq[mf], b0q[nf], acc[mf][nf]);
        __builtin_amdgcn_s_setprio(0);
        BAR();
        // ---- phase 1: quadrant (0,1) ----
#pragma unroll
        for (int nf = 0; nf < 2; ++nf) b1q[nf] = LDB(kt, 1, nf);
        if (kt + 1 < NT) STAGE(Bm, n0 + 128, N - 1, kt + 1, 1, 1);
        BAR();
        __builtin_amdgcn_s_setprio(1);
#pragma unroll
        for (int mf = 0; mf < 4; ++mf)
#pragma unroll
            for (int nf = 0; nf < 2; ++nf)
                acc[mf][2 + nf] = MFMA16(aq[mf], b1q[nf], acc[mf][2 + nf]);
        __builtin_amdgcn_s_setprio(0);
        BAR();
        // ---- phase 2: quadrant (1,1) ----
#pragma unroll
        for (int mf = 0; mf < 4; ++mf) aq[mf] = LDA(kt, 1, mf);
        BAR();
        __builtin_amdgcn_s_setprio(1);
#pragma unroll
        for (int mf = 0; mf < 4; ++mf)
#pragma unroll
            for (int nf = 0; nf < 2; ++nf)
                acc[4 + mf][2 + nf] = MFMA16(aq[mf], b1q[nf], acc[4 + mf][2 + nf]);
        __builtin_amdgcn_s_setprio(0);
        BAR();
        // ---- phase 3: quadrant (1,0) ----
        if (kt + 2 < NT) STAGE(A, m0, M - 1, kt + 2, 0, 0);   // safe: all cur-buf reads done
        BAR();
        __builtin_amdgcn_s_setprio(1);
#pragma unroll
        for (int mf = 0; mf < 4; ++mf)
#pragma unroll
            for (int nf = 0; nf < 2; ++nf)
                acc[4 + mf][nf] = MFMA16(aq[mf], b0q[nf], acc[4 + mf][nf]);
        __builtin_amdgcn_s_setprio(0);
        if (kt + 1 < NT) {
            if (kt + 2 < NT) asm volatile("s_waitcnt vmcnt(1)" ::: "memory");
            else             asm volatile("s_waitcnt vmcnt(0)" ::: "memory");
        }
        BAR();
    }

    // ---- epilogue ----
    float biasv[4];
#pragma unroll
    for (int an = 0; an < 4; ++an) biasv[an] = bias[n0 + wn * 64 + an * 16 + lr];

#pragma unroll
    for (int am = 0; am < 8; ++am) {
#pragma unroll
        for (int r = 0; r < 4; ++r) {
            int row = m0 + wm * 128 + am * 16 + lg * 4 + r;
            if (row >= M) continue;
            if (MODE == 0) {
                int bb = row / S_;
                int ss = row - bb * S_;
#pragma unroll
                for (int an = 0; an < 4; ++an) {
                    int col = n0 + wn * 64 + an * 16 + lr;
                    int hh = col >> 6, dd = col & 63;
                    float v = (acc[am][an][r] + biasv[an]) * scl;
                    outB[(((size_t)bb * H_ + hh) * S_ + ss) * D_ + dd] = f2bf(v);
                }
            } else if (MODE == 1) {
                size_t base = (size_t)row * N;
#pragma unroll
                for (int an = 0; an < 4; ++an) {
                    int col = n0 + wn * 64 + an * 16 + lr;
                    outF[base + col] = acc[am][an][r] + biasv[an] + res[base + col];
                }
            } else {
                size_t base = (size_t)row * N;
#pragma unroll
                for (int an = 0; an < 4; ++an) {
                    int col = n0 + wn * 64 + an * 16 + lr;
                    float x = acc[am][an][r] + biasv[an];
                    float u = 0.7978845608028654f * (x + 0.044715f * x * x * x);
                    float t = tanhf(u);
                    outB[base + col] = f2bf(0.5f * x * (1.0f + t));
                }
            }
        }
    }
}

// ---------------- fused attention: one WG per (b,h) ----------------
__global__ __launch_bounds__(256)
void attn_kernel(const u16* __restrict__ qg_, const u16* __restrict__ kg_,
                 const u16* __restrict__ vg_, const u16* __restrict__ msum,
                 u16* __restrict__ ctx)
{
    __shared__ u16 Ks[272 * 72];
    __shared__ u16 Vt[64 * 296];
    __shared__ u16 Ps[4][16 * 32];
    const int bh = blockIdx.x;
    const int b = bh >> 4, hh = bh & 15;
    const u16* kg = kg_ + (size_t)bh * (S_ * D_);
    const u16* vg = vg_ + (size_t)bh * (S_ * D_);
    const u16* qg = qg_ + (size_t)bh * (S_ * D_);
    const int tid = threadIdx.x, lane = tid & 63, wv = tid >> 6;

    for (int c = tid; c < (S_ * D_) / 8; c += 256) {
        int s = c >> 3, d8 = (c & 7) << 3;
        s16x8 val = *(const s16x8*)(kg + s * 64 + d8);
        *(s16x8*)&Ks[s * 72 + d8] = val;
    }
    for (int idx = tid; idx < 15 * 64; idx += 256) {
        int rr = 257 + (idx >> 6), cc = idx & 63;
        Ks[rr * 72 + cc] = 0;
    }
    for (int c = tid; c < (S_ * D_) / 8; c += 256) {
        int s = c >> 3, d8 = (c & 7) << 3;
        s16x8 val = *(const s16x8*)(vg + s * 64 + d8);
#pragma unroll
        for (int j = 0; j < 8; ++j) Vt[(d8 + j) * 296 + s] = (u16)val[j];
    }
    for (int idx = tid; idx < 64 * 39; idx += 256) {
        int dd = idx / 39, cc = 257 + idx % 39;
        Vt[dd * 296 + cc] = 0;
    }
    __syncthreads();

    const int lr = lane & 15, lg = lane >> 4;
    for (int qb = wv; qb < 17; qb += 4) {
        const int q0 = qb * 16;
        int qrow = q0 + lr; if (qrow > S_ - 1) qrow = S_ - 1;
        s16x8 aq0 = *(const s16x8*)(qg + qrow * 64 + lg * 8);
        s16x8 aq1 = *(const s16x8*)(qg + qrow * 64 + 32 + lg * 8);

        f32x4 sc[17];
#pragma unroll
        for (int t = 0; t < 17; ++t) { f32x4 z = {0.f, 0.f, 0.f, 0.f}; sc[t] = z; }
#pragma unroll
        for (int t = 0; t < 17; ++t) {
            s16x8 b0 = *(const s16x8*)&Ks[(t * 16 + lr) * 72 + lg * 8];
            s16x8 b1 = *(const s16x8*)&Ks[(t * 16 + lr) * 72 + 32 + lg * 8];
            sc[t] = MFMA16(aq0, b0, sc[t]);
            sc[t] = MFMA16(aq1, b1, sc[t]);
        }
        float mx[4] = {-3e38f, -3e38f, -3e38f, -3e38f};
#pragma unroll
        for (int r = 0; r < 4; ++r) {
            int sq = q0 + lg * 4 + r; if (sq > S_ - 1) sq = S_ - 1;
            const u16* mrow = msum + ((size_t)b * S_ + sq) * 272;
#pragma unroll
            for (int t = 0; t < 17; ++t) {
                sc[t][r] += bf2f(mrow[t * 16 + lr]);
                mx[r] = fmaxf(mx[r], sc[t][r]);
            }
        }
#pragma unroll
        for (int r = 0; r < 4; ++r) {
#pragma unroll
            for (int xm = 1; xm <= 8; xm <<= 1)
                mx[r] = fmaxf(mx[r], __shfl_xor(mx[r], xm, 64));
        }
        float sum[4] = {0.f, 0.f, 0.f, 0.f};
#pragma unroll
        for (int t = 0; t < 17; ++t)
#pragma unroll
            for (int r = 0; r < 4; ++r) {
                float e = __expf(sc[t][r] - mx[r]);
                sc[t][r] = e; sum[r] += e;
            }
#pragma unroll
        for (int r = 0; r < 4; ++r) {
#pragma unroll
            for (int xm = 1; xm <= 8; xm <<= 1)
                sum[r] += __shfl_xor(sum[r], xm, 64);
        }

        f32x4 ac[4];
#pragma unroll
        for (int nt = 0; nt < 4; ++nt) { f32x4 z = {0.f, 0.f, 0.f, 0.f}; ac[nt] = z; }
        u16* myP = &Ps[wv][0];
#pragma unroll
        for (int kc = 0; kc < 9; ++kc) {
#pragma unroll
            for (int tt = 0; tt < 2; ++tt) {
                const int t = kc * 2 + tt;
#pragma unroll
                for (int r = 0; r < 4; ++r) {
                    float pv = (t < 17) ? sc[(t < 17) ? t : 0][r] : 0.f;
                    myP[(lg * 4 + r) * 32 + tt * 16 + lr] = f2bf(pv);
                }
            }
            s16x8 pa = *(const s16x8*)&myP[lr * 32 + lg * 8];
#pragma unroll
            for (int nt = 0; nt < 4; ++nt) {
                s16x8 bv = *(const s16x8*)&Vt[(nt * 16 + lr) * 296 + kc * 32 + lg * 8];
                ac[nt] = MFMA16(pa, bv, ac[nt]);
            }
        }
#pragma unroll
        for (int r = 0; r < 4; ++r) {
            int sq = q0 + lg * 4 + r;
            if (sq < S_) {
                float rd = 1.0f / sum[r];
                size_t base = (((size_t)b * S_ + sq) * H_ + hh) * D_;
#pragma unroll
                for (int nt = 0; nt < 4; ++nt)
                    ctx[base + nt * 16 + lr] = f2bf(ac[nt][r] * rd);
            }
        }
    }
}

// ---------------- launch ----------------
extern "C" void kernel_launch(void* const* d_in, const int* in_sizes, int n_in,
                              void* d_out, int out_size, void* d_ws, size_t ws_size,
                              hipStream_t stream)
{
    const float* hid   = (const float*)d_in[0];
    const float* am    = (const float*)d_in[1];
    const float* cm    = (const float*)d_in[2];
    const float* ln1w  = (const float*)d_in[3];
    const float* ln1b  = (const float*)d_in[4];
    const float* qw    = (const float*)d_in[5];
    const float* qbias = (const float*)d_in[6];
    const float* kw    = (const float*)d_in[7];
    const float* kbias = (const float*)d_in[8];
    const float* vw    = (const float*)d_in[9];
    const float* vbias = (const float*)d_in[10];
    const float* ow    = (const float*)d_in[11];
    const float* obias = (const float*)d_in[12];
    const float* ln2w  = (const float*)d_in[13];
    const float* ln2b  = (const float*)d_in[14];
    const float* f1w   = (const float*)d_in[15];
    const float* f1b   = (const float*)d_in[16];
    const float* f2w   = (const float*)d_in[17];
    const float* f2b   = (const float*)d_in[18];
    float* out = (float*)d_out;

    const size_t ME = (size_t)M_ * E_;
    u16* Wq   = (u16*)d_ws;
    u16* Wk   = Wq + 1048576;
    u16* Wv   = Wk + 1048576;
    u16* Wo   = Wv + 1048576;
    u16* Wf1  = Wo + 1048576;
    u16* Wf2  = Wf1 + 4 * 1048576;
    u16* xln  = Wf2 + 4 * 1048576;
    u16* qb_  = xln + ME;
    u16* kb_  = qb_ + ME;
    u16* vb_  = kb_ + ME;
    u16* ctx  = vb_ + ME;
    float* hbuf = (float*)(ctx + ME);
    u16* msum = (u16*)(hbuf + ME);
    u16* act  = qb_;      // reuse q..ctx region = M x I bf16 (exact fit)
    u16* x2   = xln;

    convert_w_kernel<<<3072, 256, 0, stream>>>(qw, kw, vw, ow, f1w, f2w, Wq);
    mask_combine_kernel<<<8736, 256, 0, stream>>>(am, cm, msum);
    ln_kernel<<<M_, 256, 0, stream>>>(hid, ln1w, ln1b, xln);
    gemm8<0><<<dim3(12, 33), 512, 0, stream>>>(xln, Wq, Wk, Wv, qbias, kbias, vbias,
                                               nullptr, nullptr, qb_, kb_, vb_,
                                               M_, 1024, 1024);
    attn_kernel<<<512, 256, 0, stream>>>(qb_, kb_, vb_, msum, ctx);
    gemm8<1><<<dim3(4, 33), 512, 0, stream>>>(ctx, Wo, nullptr, nullptr, obias, nullptr, nullptr,
                                              hid, hbuf, nullptr, nullptr, nullptr,
                                              M_, 1024, 1024);
    ln_kernel<<<M_, 256, 0, stream>>>(hbuf, ln2w, ln2b, x2);
    gemm8<2><<<dim3(16, 33), 512, 0, stream>>>(x2, Wf1, nullptr, nullptr, f1b, nullptr, nullptr,
                                               nullptr, nullptr, act, nullptr, nullptr,
                                               M_, 4096, 1024);
    gemm8<1><<<dim3(4, 33), 512, 0, stream>>>(act, Wf2, nullptr, nullptr, f2b, nullptr, nullptr,
                                              hbuf, out, nullptr, nullptr, nullptr,
                                              M_, 1024, 4096);
}

// Round 3
// 451.238 us; speedup vs baseline: 1.0292x; 1.0292x over previous
//
#include <hip/hip_runtime.h>

typedef unsigned short u16;
typedef unsigned int   u32;
typedef short s16x8 __attribute__((ext_vector_type(8)));
typedef float f32x4 __attribute__((ext_vector_type(4)));

#define MFMA16(A,B,C) __builtin_amdgcn_mfma_f32_16x16x32_bf16((A),(B),(C),0,0,0)
#define BAR()  asm volatile("s_barrier" ::: "memory")
#define LGKM0  asm volatile("s_waitcnt lgkmcnt(0)" ::: "memory")
#define VMC2   asm volatile("s_waitcnt vmcnt(2)" ::: "memory")
#define VMC0   asm volatile("s_waitcnt vmcnt(0)" ::: "memory")

#define B_   32
#define S_   257
#define E_   1024
#define H_   16
#define D_   64
#define I_   4096
#define M_   (B_*S_)   // 8224

__device__ __forceinline__ u16 f2bf(float f) {
    u32 u = __float_as_uint(f);
    u32 r = u + 0x7fffu + ((u >> 16) & 1u);
    return (u16)(r >> 16);
}
__device__ __forceinline__ float bf2f(u16 b) {
    return __uint_as_float(((u32)b) << 16);
}

__device__ __forceinline__ void gload16(const void* g, void* l) {
    __builtin_amdgcn_global_load_lds(
        (const __attribute__((address_space(1))) u32*)g,
        (__attribute__((address_space(3))) u32*)l, 16, 0, 0);
}

// ---------------- weight fp32 -> bf16 convert (12M elems) ----------------
__global__ __launch_bounds__(256)
void convert_w_kernel(const float* __restrict__ qw, const float* __restrict__ kw,
                      const float* __restrict__ vw, const float* __restrict__ ow,
                      const float* __restrict__ f1, const float* __restrict__ f2,
                      u16* __restrict__ dst)
{
    const int total4 = (12 * 1048576) / 4;
    for (int i = blockIdx.x * 256 + threadIdx.x; i < total4; i += gridDim.x * 256) {
        int e = i * 4;
        int seg = e >> 20;
        const float* srcp; int off;
        if (seg < 4)      { srcp = (seg == 0 ? qw : seg == 1 ? kw : seg == 2 ? vw : ow); off = e & 1048575; }
        else if (seg < 8) { srcp = f1; off = e - 4 * 1048576; }
        else              { srcp = f2; off = e - 8 * 1048576; }
        float4 v = *(const float4*)(srcp + off);
        ushort4 o;
        o.x = f2bf(v.x); o.y = f2bf(v.y); o.z = f2bf(v.z); o.w = f2bf(v.w);
        *(ushort4*)(dst + e) = o;
    }
}

// ---------------- combined mask table: msum[b][sq][272] bf16 ----------------
__global__ __launch_bounds__(256)
void mask_combine_kernel(const float* __restrict__ am, const float* __restrict__ cm,
                         u16* __restrict__ msum)
{
    const int total = B_ * S_ * 272;
    for (int i = blockIdx.x * 256 + threadIdx.x; i < total; i += gridDim.x * 256) {
        int skv = i % 272;
        int rem = i / 272;
        int sq  = rem % S_;
        int b   = rem / S_;
        float v;
        if (skv < S_) {
            size_t o = ((size_t)b * S_ + sq) * S_ + skv;
            v = am[o] + cm[o];
        } else v = -1e30f;
        msum[i] = f2bf(v);
    }
}

// ---------------- LayerNorm row kernel ----------------
__global__ __launch_bounds__(256)
void ln_kernel(const float* __restrict__ src, const float* __restrict__ gam,
               const float* __restrict__ bet, u16* __restrict__ dst)
{
    int row = blockIdx.x;
    const float4* p = (const float4*)(src + (size_t)row * E_);
    float4 x = p[threadIdx.x];
    float s  = x.x + x.y + x.z + x.w;
    float s2 = x.x * x.x + x.y * x.y + x.z * x.z + x.w * x.w;
#pragma unroll
    for (int xm = 1; xm < 64; xm <<= 1) {
        s  += __shfl_xor(s,  xm, 64);
        s2 += __shfl_xor(s2, xm, 64);
    }
    __shared__ float red[8];
    int wv = threadIdx.x >> 6;
    if ((threadIdx.x & 63) == 0) { red[wv] = s; red[4 + wv] = s2; }
    __syncthreads();
    s  = red[0] + red[1] + red[2] + red[3];
    s2 = red[4] + red[5] + red[6] + red[7];
    float mu  = s * (1.0f / 1024.0f);
    float var = s2 * (1.0f / 1024.0f) - mu * mu;
    float rs  = rsqrtf(var + 1e-5f);
    float4 g  = ((const float4*)gam)[threadIdx.x];
    float4 be = ((const float4*)bet)[threadIdx.x];
    ushort4 o;
    o.x = f2bf((x.x - mu) * rs * g.x + be.x);
    o.y = f2bf((x.y - mu) * rs * g.y + be.y);
    o.z = f2bf((x.z - mu) * rs * g.z + be.z);
    o.w = f2bf((x.w - mu) * rs * g.w + be.w);
    ((ushort4*)dst)[(size_t)row * 256 + threadIdx.x] = o;
}

// ======== 256x256 8-phase NT GEMM, BK=64, 8 waves, 128 KB LDS (m201 port) ====
// C[m][n] = sum_k A[m][k]*B[n][k]
// MODE 0: fused QKV -> bf16 [B,H,S,D] (q scaled 1/8); MODE 1: f32 acc+bias+res
// MODE 2: bf16 gelu(acc+bias); MODE 3: f32 partial (split-K, no bias)
// LDS halves [128 rows][64 cols] bf16; swizzle: byte ^= ((row&7)<<4)
// (inverse applied to per-lane global src; gload_lds dest stays linear)
template<int MODE>
__global__ __launch_bounds__(512, 2)
void gemm8(const u16* __restrict__ A,
           const u16* __restrict__ Bq, const u16* __restrict__ Bk, const u16* __restrict__ Bv,
           const float* __restrict__ biasq, const float* __restrict__ biask, const float* __restrict__ biasvv,
           const float* __restrict__ res, float* __restrict__ outF, float* __restrict__ outF1,
           u16* __restrict__ outBq, u16* __restrict__ outBk, u16* __restrict__ outBv,
           int M, int N, int Ks, int klen)
{
    __shared__ u16 lds[2][4][8192];   // [buf][A0,A1,B0,B1][128x64] = 128 KB
    const int tid = threadIdx.x, lane = tid & 63, w = tid >> 6;
    const int lr = lane & 15, lg = lane >> 4;
    const int wm = w >> 2, wn = w & 3;          // 2 x 4 wave grid

    const u16* Bm = Bq; const float* bias = biasq; u16* outB = outBq;
    float scl = 1.0f; int nt = blockIdx.x; int k0 = 0; float* outP = outF;
    if (MODE == 0) {
        int mat = nt >> 2; nt &= 3;
        if (mat == 1)      { Bm = Bk; bias = biask; outB = outBk; }
        else if (mat == 2) { Bm = Bv; bias = biasvv; outB = outBv; }
        if (mat == 0) scl = 0.125f;             // D^-0.5
    } else if (MODE == 3) {
        int kz = nt & 1; nt >>= 1;
        k0 = kz * klen;
        if (kz) outP = outF1;
    }
    const int m0 = blockIdx.y * 256, n0 = nt * 256;
    const int NT = klen >> 6, NI = klen >> 7;
    const int tb = k0 >> 6;

    // staging precompute: dest byte p -> (row, col) after inverse swizzle
    {
    }
    const int p    = w * 1024 + lane * 16;
    const int lby  = p ^ (((p >> 7) & 7) << 4);
    const int srow = lby >> 7;            // 0..63 (sub-stage adds 64)
    const int scol = (lby & 127) >> 1;    // element col, 8-aligned

    auto STAGE = [&](int buf, int half, const u16* src, int grow0, int rowmax, int t) {
#pragma unroll
        for (int s = 0; s < 2; ++s) {
            int gr = grow0 + s * 64 + srow; if (gr > rowmax) gr = rowmax;
            gload16(src + (size_t)gr * Ks + ((tb + t) << 6) + scol,
                    (char*)&lds[buf][half][0] + s * 8192 + w * 1024);
        }
    };
    auto LDA = [&](int buf, int mh, int mf, int kh) -> s16x8 {
        const char* b = (const char*)&lds[buf][wm][0];
        int inrow = mh * 64 + mf * 16 + lr;
        return *(const s16x8*)(b + inrow * 128 + ((kh * 64 + lg * 16) ^ ((lr & 7) << 4)));
    };
    auto LDB = [&](int buf, int nh, int nf, int kh) -> s16x8 {
        const char* b = (const char*)&lds[buf][2 + (wn >> 1)][0];
        int inrow = (wn & 1) * 64 + nh * 32 + nf * 16 + lr;
        return *(const s16x8*)(b + inrow * 128 + ((kh * 64 + lg * 16) ^ ((lr & 7) << 4)));
    };

    f32x4 acc[8][4];
#pragma unroll
    for (int i = 0; i < 8; ++i)
#pragma unroll
        for (int j = 0; j < 4; ++j) { f32x4 z = {0.f, 0.f, 0.f, 0.f}; acc[i][j] = z; }

    s16x8 a[4][2], b[2][2][2];
    auto MFQ = [&](int mh, int nh) {
        __builtin_amdgcn_s_setprio(1);
#pragma unroll
        for (int mf = 0; mf < 4; ++mf)
#pragma unroll
            for (int nf = 0; nf < 2; ++nf)
#pragma unroll
                for (int kh = 0; kh < 2; ++kh)
                    acc[mh * 4 + mf][nh * 2 + nf] =
                        MFMA16(a[mf][kh], b[nh][nf][kh], acc[mh * 4 + mf][nh * 2 + nf]);
        __builtin_amdgcn_s_setprio(0);
    };

    // ---- prologue: tile0 fully + tile1.a0; wait tile0 (leave a0 in flight) ----
    STAGE(0, 0, A,  m0,       M - 1, 0);
    STAGE(0, 1, A,  m0 + 128, M - 1, 0);
    STAGE(0, 2, Bm, n0,       N - 1, 0);
    STAGE(0, 3, Bm, n0 + 128, N - 1, 0);
    STAGE(1, 0, A,  m0,       M - 1, 1);
    VMC2;
    BAR();

    for (int i = 0; i < NI; ++i) {
        const int t1 = 2 * i + 1, t2 = 2 * i + 2, t3 = 2 * i + 3;
        const bool more = (i + 1 < NI);
        // ---- phase 1: tile t0 quad(0,0); stage t1.a1 ----
#pragma unroll
        for (int mf = 0; mf < 4; ++mf)
#pragma unroll
            for (int kh = 0; kh < 2; ++kh) a[mf][kh] = LDA(0, 0, mf, kh);
#pragma unroll
        for (int nf = 0; nf < 2; ++nf)
#pragma unroll
            for (int kh = 0; kh < 2; ++kh) b[0][nf][kh] = LDB(0, 0, nf, kh);
        STAGE(1, 1, A, m0 + 128, M - 1, t1);
        BAR(); LGKM0;
        MFQ(0, 0);
        BAR();
        // ---- phase 2: quad(0,1); stage t1.b0 ----
#pragma unroll
        for (int nf = 0; nf < 2; ++nf)
#pragma unroll
            for (int kh = 0; kh < 2; ++kh) b[1][nf][kh] = LDB(0, 1, nf, kh);
        STAGE(1, 2, Bm, n0, N - 1, t1);
        BAR(); LGKM0;
        MFQ(0, 1);
        BAR();
        // ---- phase 3: quad(1,1); stage t1.b1 ----
#pragma unroll
        for (int mf = 0; mf < 4; ++mf)
#pragma unroll
            for (int kh = 0; kh < 2; ++kh) a[mf][kh] = LDA(0, 1, mf, kh);
        STAGE(1, 3, Bm, n0 + 128, N - 1, t1);
        BAR(); LGKM0;
        MFQ(1, 1);
        BAR();
        // ---- phase 4: quad(1,0); stage t2.a0; counted vmcnt ----
        if (more) STAGE(0, 0, A, m0, M - 1, t2);
        MFQ(1, 0);
        if (more) { VMC2; } else { VMC0; }
        BAR();
        // ---- phase 5: tile t1 quad(0,0); stage t2.b0 ----
#pragma unroll
        for (int mf = 0; mf < 4; ++mf)
#pragma unroll
            for (int kh = 0; kh < 2; ++kh) a[mf][kh] = LDA(1, 0, mf, kh);
#pragma unroll
        for (int nf = 0; nf < 2; ++nf)
#pragma unroll
            for (int kh = 0; kh < 2; ++kh) b[0][nf][kh] = LDB(1, 0, nf, kh);
        if (more) STAGE(0, 2, Bm, n0, N - 1, t2);
        BAR(); LGKM0;
        MFQ(0, 0);
        BAR();
        // ---- phase 6: quad(0,1); stage t2.b1 ----
#pragma unroll
        for (int nf = 0; nf < 2; ++nf)
#pragma unroll
            for (int kh = 0; kh < 2; ++kh) b[1][nf][kh] = LDB(1, 1, nf, kh);
        if (more) STAGE(0, 3, Bm, n0 + 128, N - 1, t2);
        BAR(); LGKM0;
        MFQ(0, 1);
        BAR();
        // ---- phase 7: quad(1,1); stage t2.a1 ----
#pragma unroll
        for (int mf = 0; mf < 4; ++mf)
#pragma unroll
            for (int kh = 0; kh < 2; ++kh) a[mf][kh] = LDA(1, 1, mf, kh);
        if (more) STAGE(0, 1, A, m0 + 128, M - 1, t2);
        BAR(); LGKM0;
        MFQ(1, 1);
        BAR();
        // ---- phase 8: quad(1,0); stage t3.a0; counted vmcnt ----
        if (more) STAGE(1, 0, A, m0, M - 1, t3);
        MFQ(1, 0);
        if (more) VMC2;
        BAR();
    }

    // ---- epilogue ----
    float biasv[4];
    if (MODE != 3) {
#pragma unroll
        for (int an = 0; an < 4; ++an)
            biasv[an] = bias[n0 + wn * 64 + (an >> 1) * 32 + (an & 1) * 16 + lr];
    }
#pragma unroll
    for (int am = 0; am < 8; ++am) {
#pragma unroll
        for (int r = 0; r < 4; ++r) {
            int row = m0 + wm * 128 + (am >> 2) * 64 + (am & 3) * 16 + lg * 4 + r;
            if (row >= M) continue;
            if (MODE == 0) {
                int bb = row / S_;
                int ss = row - bb * S_;
#pragma unroll
                for (int an = 0; an < 4; ++an) {
                    int col = n0 + wn * 64 + (an >> 1) * 32 + (an & 1) * 16 + lr;
                    int hh = col >> 6, dd = col & 63;
                    float v = (acc[am][an][r] + biasv[an]) * scl;
                    outB[(((size_t)bb * H_ + hh) * S_ + ss) * D_ + dd] = f2bf(v);
                }
            } else if (MODE == 1) {
                size_t base = (size_t)row * N;
#pragma unroll
                for (int an = 0; an < 4; ++an) {
                    int col = n0 + wn * 64 + (an >> 1) * 32 + (an & 1) * 16 + lr;
                    outF[base + col] = acc[am][an][r] + biasv[an] + res[base + col];
                }
            } else if (MODE == 2) {
                size_t base = (size_t)row * N;
#pragma unroll
                for (int an = 0; an < 4; ++an) {
                    int col = n0 + wn * 64 + (an >> 1) * 32 + (an & 1) * 16 + lr;
                    float x = acc[am][an][r] + biasv[an];
                    float u = 0.7978845608028654f * (x + 0.044715f * x * x * x);
                    float t = tanhf(u);
                    outB[base + col] = f2bf(0.5f * x * (1.0f + t));
                }
            } else {
                size_t base = (size_t)row * N;
#pragma unroll
                for (int an = 0; an < 4; ++an) {
                    int col = n0 + wn * 64 + (an >> 1) * 32 + (an & 1) * 16 + lr;
                    outP[base + col] = acc[am][an][r];
                }
            }
        }
    }
}

// ---------------- split-K reduce: out = P0 + P1 + bias + res ----------------
__global__ __launch_bounds__(256)
void fc2_reduce(const float* __restrict__ P0, const float* __restrict__ P1,
                const float* __restrict__ res, const float* __restrict__ bias,
                float* __restrict__ out)
{
    const int n4 = (M_ * E_) / 4;
    for (int i = blockIdx.x * 256 + threadIdx.x; i < n4; i += gridDim.x * 256) {
        float4 x0 = ((const float4*)P0)[i];
        float4 x1 = ((const float4*)P1)[i];
        float4 rr = ((const float4*)res)[i];
        float4 bb = ((const float4*)bias)[i & 255];
        float4 o;
        o.x = x0.x + x1.x + rr.x + bb.x;
        o.y = x0.y + x1.y + rr.y + bb.y;
        o.z = x0.z + x1.z + rr.z + bb.z;
        o.w = x0.w + x1.w + rr.w + bb.w;
        ((float4*)out)[i] = o;
    }
}

// ---------------- fused attention: one WG per (b,h) ----------------
__global__ __launch_bounds__(256)
void attn_kernel(const u16* __restrict__ qg_, const u16* __restrict__ kg_,
                 const u16* __restrict__ vg_, const u16* __restrict__ msum,
                 u16* __restrict__ ctx)
{
    __shared__ u16 Ks[272 * 72];
    __shared__ u16 Vt[64 * 296];
    __shared__ u16 Ps[4][16 * 32];
    const int bh = blockIdx.x;
    const int b = bh >> 4, hh = bh & 15;
    const u16* kg = kg_ + (size_t)bh * (S_ * D_);
    const u16* vg = vg_ + (size_t)bh * (S_ * D_);
    const u16* qg = qg_ + (size_t)bh * (S_ * D_);
    const int tid = threadIdx.x, lane = tid & 63, wv = tid >> 6;

    for (int c = tid; c < (S_ * D_) / 8; c += 256) {
        int s = c >> 3, d8 = (c & 7) << 3;
        s16x8 val = *(const s16x8*)(kg + s * 64 + d8);
        *(s16x8*)&Ks[s * 72 + d8] = val;
    }
    for (int idx = tid; idx < 15 * 64; idx += 256) {
        int rr = 257 + (idx >> 6), cc = idx & 63;
        Ks[rr * 72 + cc] = 0;
    }
    for (int c = tid; c < (S_ * D_) / 8; c += 256) {
        int s = c >> 3, d8 = (c & 7) << 3;
        s16x8 val = *(const s16x8*)(vg + s * 64 + d8);
#pragma unroll
        for (int j = 0; j < 8; ++j) Vt[(d8 + j) * 296 + s] = (u16)val[j];
    }
    for (int idx = tid; idx < 64 * 39; idx += 256) {
        int dd = idx / 39, cc = 257 + idx % 39;
        Vt[dd * 296 + cc] = 0;
    }
    __syncthreads();

    const int lr = lane & 15, lg = lane >> 4;
    for (int qb = wv; qb < 17; qb += 4) {
        const int q0 = qb * 16;
        int qrow = q0 + lr; if (qrow > S_ - 1) qrow = S_ - 1;
        s16x8 aq0 = *(const s16x8*)(qg + qrow * 64 + lg * 8);
        s16x8 aq1 = *(const s16x8*)(qg + qrow * 64 + 32 + lg * 8);

        f32x4 sc[17];
#pragma unroll
        for (int t = 0; t < 17; ++t) { f32x4 z = {0.f, 0.f, 0.f, 0.f}; sc[t] = z; }
#pragma unroll
        for (int t = 0; t < 17; ++t) {
            s16x8 b0 = *(const s16x8*)&Ks[(t * 16 + lr) * 72 + lg * 8];
            s16x8 b1 = *(const s16x8*)&Ks[(t * 16 + lr) * 72 + 32 + lg * 8];
            sc[t] = MFMA16(aq0, b0, sc[t]);
            sc[t] = MFMA16(aq1, b1, sc[t]);
        }
        float mx[4] = {-3e38f, -3e38f, -3e38f, -3e38f};
#pragma unroll
        for (int r = 0; r < 4; ++r) {
            int sq = q0 + lg * 4 + r; if (sq > S_ - 1) sq = S_ - 1;
            const u16* mrow = msum + ((size_t)b * S_ + sq) * 272;
#pragma unroll
            for (int t = 0; t < 17; ++t) {
                sc[t][r] += bf2f(mrow[t * 16 + lr]);
                mx[r] = fmaxf(mx[r], sc[t][r]);
            }
        }
#pragma unroll
        for (int r = 0; r < 4; ++r) {
#pragma unroll
            for (int xm = 1; xm <= 8; xm <<= 1)
                mx[r] = fmaxf(mx[r], __shfl_xor(mx[r], xm, 64));
        }
        float sum[4] = {0.f, 0.f, 0.f, 0.f};
#pragma unroll
        for (int t = 0; t < 17; ++t)
#pragma unroll
            for (int r = 0; r < 4; ++r) {
                float e = __expf(sc[t][r] - mx[r]);
                sc[t][r] = e; sum[r] += e;
            }
#pragma unroll
        for (int r = 0; r < 4; ++r) {
#pragma unroll
            for (int xm = 1; xm <= 8; xm <<= 1)
                sum[r] += __shfl_xor(sum[r], xm, 64);
        }

        f32x4 ac[4];
#pragma unroll
        for (int nt = 0; nt < 4; ++nt) { f32x4 z = {0.f, 0.f, 0.f, 0.f}; ac[nt] = z; }
        u16* myP = &Ps[wv][0];
#pragma unroll
        for (int kc = 0; kc < 9; ++kc) {
#pragma unroll
            for (int tt = 0; tt < 2; ++tt) {
                const int t = kc * 2 + tt;
#pragma unroll
                for (int r = 0; r < 4; ++r) {
                    float pv = (t < 17) ? sc[(t < 17) ? t : 0][r] : 0.f;
                    myP[(lg * 4 + r) * 32 + tt * 16 + lr] = f2bf(pv);
                }
            }
            s16x8 pa = *(const s16x8*)&myP[lr * 32 + lg * 8];
#pragma unroll
            for (int nt = 0; nt < 4; ++nt) {
                s16x8 bv = *(const s16x8*)&Vt[(nt * 16 + lr) * 296 + kc * 32 + lg * 8];
                ac[nt] = MFMA16(pa, bv, ac[nt]);
            }
        }
#pragma unroll
        for (int r = 0; r < 4; ++r) {
            int sq = q0 + lg * 4 + r;
            if (sq < S_) {
                float rd = 1.0f / sum[r];
                size_t base = (((size_t)b * S_ + sq) * H_ + hh) * D_;
#pragma unroll
                for (int nt = 0; nt < 4; ++nt)
                    ctx[base + nt * 16 + lr] = f2bf(ac[nt][r] * rd);
            }
        }
    }
}

// ---------------- launch ----------------
extern "C" void kernel_launch(void* const* d_in, const int* in_sizes, int n_in,
                              void* d_out, int out_size, void* d_ws, size_t ws_size,
                              hipStream_t stream)
{
    const float* hid   = (const float*)d_in[0];
    const float* am    = (const float*)d_in[1];
    const float* cm    = (const float*)d_in[2];
    const float* ln1w  = (const float*)d_in[3];
    const float* ln1b  = (const float*)d_in[4];
    const float* qw    = (const float*)d_in[5];
    const float* qbias = (const float*)d_in[6];
    const float* kw    = (const float*)d_in[7];
    const float* kbias = (const float*)d_in[8];
    const float* vw    = (const float*)d_in[9];
    const float* vbias = (const float*)d_in[10];
    const float* ow    = (const float*)d_in[11];
    const float* obias = (const float*)d_in[12];
    const float* ln2w  = (const float*)d_in[13];
    const float* ln2b  = (const float*)d_in[14];
    const float* f1w   = (const float*)d_in[15];
    const float* f1b   = (const float*)d_in[16];
    const float* f2w   = (const float*)d_in[17];
    const float* f2b   = (const float*)d_in[18];
    float* out = (float*)d_out;

    const size_t ME = (size_t)M_ * E_;
    u16* Wq   = (u16*)d_ws;
    u16* Wk   = Wq + 1048576;
    u16* Wv   = Wk + 1048576;
    u16* Wo   = Wv + 1048576;
    u16* Wf1  = Wo + 1048576;
    u16* Wf2  = Wf1 + 4 * 1048576;
    u16* xln  = Wf2 + 4 * 1048576;
    u16* qb_  = xln + ME;
    u16* kb_  = qb_ + ME;
    u16* vb_  = kb_ + ME;
    u16* ctx  = vb_ + ME;
    float* hbuf = (float*)(ctx + ME);
    u16* msum = (u16*)(hbuf + ME);
    u16* act  = qb_;      // reuse q..ctx region = M x I bf16 (exact fit)
    u16* x2   = xln;
    float* P0 = (float*)(msum + (size_t)B_ * S_ * 272);
    float* P1 = P0 + ME;
    const size_t need = (size_t)((char*)(P1 + ME) - (char*)d_ws);
    const bool split = ws_size >= need;

    convert_w_kernel<<<3072, 256, 0, stream>>>(qw, kw, vw, ow, f1w, f2w, Wq);
    mask_combine_kernel<<<8736, 256, 0, stream>>>(am, cm, msum);
    ln_kernel<<<M_, 256, 0, stream>>>(hid, ln1w, ln1b, xln);
    gemm8<0><<<dim3(12, 33), 512, 0, stream>>>(xln, Wq, Wk, Wv, qbias, kbias, vbias,
                                               nullptr, nullptr, nullptr, qb_, kb_, vb_,
                                               M_, 1024, 1024, 1024);
    attn_kernel<<<512, 256, 0, stream>>>(qb_, kb_, vb_, msum, ctx);
    gemm8<1><<<dim3(4, 33), 512, 0, stream>>>(ctx, Wo, nullptr, nullptr, obias, nullptr, nullptr,
                                              hid, hbuf, nullptr, nullptr, nullptr, nullptr,
                                              M_, 1024, 1024, 1024);
    ln_kernel<<<M_, 256, 0, stream>>>(hbuf, ln2w, ln2b, x2);
    gemm8<2><<<dim3(16, 33), 512, 0, stream>>>(x2, Wf1, nullptr, nullptr, f1b, nullptr, nullptr,
                                               nullptr, nullptr, nullptr, act, nullptr, nullptr,
                                               M_, 4096, 1024, 1024);
    if (split) {
        gemm8<3><<<dim3(8, 33), 512, 0, stream>>>(act, Wf2, nullptr, nullptr, nullptr, nullptr, nullptr,
                                                  nullptr, P0, P1, nullptr, nullptr, nullptr,
                                                  M_, 1024, 4096, 2048);
        fc2_reduce<<<2048, 256, 0, stream>>>(P0, P1, hbuf, f2b, out);
    } else {
        gemm8<1><<<dim3(4, 33), 512, 0, stream>>>(act, Wf2, nullptr, nullptr, f2b, nullptr, nullptr,
                                                  hbuf, out, nullptr, nullptr, nullptr, nullptr,
                                                  M_, 1024, 4096, 4096);
    }
}

// Round 4
// 421.599 us; speedup vs baseline: 1.1015x; 1.0703x over previous
//
#include <hip/hip_runtime.h>

typedef unsigned short u16;
typedef unsigned int   u32;
typedef short s16x8 __attribute__((ext_vector_type(8)));
typedef float f32x4 __attribute__((ext_vector_type(4)));

#define MFMA16(A,B,C) __builtin_amdgcn_mfma_f32_16x16x32_bf16((A),(B),(C),0,0,0)
#define BAR()  asm volatile("s_barrier" ::: "memory")
#define LGKM0  asm volatile("s_waitcnt lgkmcnt(0)" ::: "memory")
#define VMC8   asm volatile("s_waitcnt vmcnt(8)" ::: "memory")
#define VMC0   asm volatile("s_waitcnt vmcnt(0)" ::: "memory")

#define B_   32
#define S_   257
#define E_   1024
#define H_   16
#define D_   64
#define I_   4096
#define M_   (B_*S_)   // 8224

__device__ __forceinline__ u16 f2bf(float f) {
    u32 u = __float_as_uint(f);
    u32 r = u + 0x7fffu + ((u >> 16) & 1u);
    return (u16)(r >> 16);
}
__device__ __forceinline__ float bf2f(u16 b) {
    return __uint_as_float(((u32)b) << 16);
}

__device__ __forceinline__ void gload16(const void* g, void* l) {
    __builtin_amdgcn_global_load_lds(
        (const __attribute__((address_space(1))) u32*)g,
        (__attribute__((address_space(3))) u32*)l, 16, 0, 0);
}

// ---------------- weight fp32 -> bf16 convert (12M elems) ----------------
__global__ __launch_bounds__(256)
void convert_w_kernel(const float* __restrict__ qw, const float* __restrict__ kw,
                      const float* __restrict__ vw, const float* __restrict__ ow,
                      const float* __restrict__ f1, const float* __restrict__ f2,
                      u16* __restrict__ dst)
{
    const int total4 = (12 * 1048576) / 4;
    for (int i = blockIdx.x * 256 + threadIdx.x; i < total4; i += gridDim.x * 256) {
        int e = i * 4;
        int seg = e >> 20;
        const float* srcp; int off;
        if (seg < 4)      { srcp = (seg == 0 ? qw : seg == 1 ? kw : seg == 2 ? vw : ow); off = e & 1048575; }
        else if (seg < 8) { srcp = f1; off = e - 4 * 1048576; }
        else              { srcp = f2; off = e - 8 * 1048576; }
        float4 v = *(const float4*)(srcp + off);
        ushort4 o;
        o.x = f2bf(v.x); o.y = f2bf(v.y); o.z = f2bf(v.z); o.w = f2bf(v.w);
        *(ushort4*)(dst + e) = o;
    }
}

// ---------------- combined mask table: msum[b][sq][272] bf16 ----------------
__global__ __launch_bounds__(256)
void mask_combine_kernel(const float* __restrict__ am, const float* __restrict__ cm,
                         u16* __restrict__ msum)
{
    const int total = B_ * S_ * 272;
    for (int i = blockIdx.x * 256 + threadIdx.x; i < total; i += gridDim.x * 256) {
        int skv = i % 272;
        int rem = i / 272;
        int sq  = rem % S_;
        int b   = rem / S_;
        float v;
        if (skv < S_) {
            size_t o = ((size_t)b * S_ + sq) * S_ + skv;
            v = am[o] + cm[o];
        } else v = -1e30f;
        msum[i] = f2bf(v);
    }
}

// ---------------- LayerNorm row kernel ----------------
__global__ __launch_bounds__(256)
void ln_kernel(const float* __restrict__ src, const float* __restrict__ gam,
               const float* __restrict__ bet, u16* __restrict__ dst)
{
    int row = blockIdx.x;
    const float4* p = (const float4*)(src + (size_t)row * E_);
    float4 x = p[threadIdx.x];
    float s  = x.x + x.y + x.z + x.w;
    float s2 = x.x * x.x + x.y * x.y + x.z * x.z + x.w * x.w;
#pragma unroll
    for (int xm = 1; xm < 64; xm <<= 1) {
        s  += __shfl_xor(s,  xm, 64);
        s2 += __shfl_xor(s2, xm, 64);
    }
    __shared__ float red[8];
    int wv = threadIdx.x >> 6;
    if ((threadIdx.x & 63) == 0) { red[wv] = s; red[4 + wv] = s2; }
    __syncthreads();
    s  = red[0] + red[1] + red[2] + red[3];
    s2 = red[4] + red[5] + red[6] + red[7];
    float mu  = s * (1.0f / 1024.0f);
    float var = s2 * (1.0f / 1024.0f) - mu * mu;
    float rs  = rsqrtf(var + 1e-5f);
    float4 g  = ((const float4*)gam)[threadIdx.x];
    float4 be = ((const float4*)bet)[threadIdx.x];
    ushort4 o;
    o.x = f2bf((x.x - mu) * rs * g.x + be.x);
    o.y = f2bf((x.y - mu) * rs * g.y + be.y);
    o.z = f2bf((x.z - mu) * rs * g.z + be.z);
    o.w = f2bf((x.w - mu) * rs * g.w + be.w);
    ((ushort4*)dst)[(size_t)row * 256 + threadIdx.x] = o;
}

// ======== 256x256 8-phase NT GEMM, BK=64, deep prefetch (vmcnt(8)) =========
// C[m][n] = sum_k A[m][k]*B[n][k]
// Halves: 0=A0,1=A1,2=B0,3=B1; per-buffer last reads: B* at P2, A* at P3.
// Stages: P3 -> t2.B0,B1 ; P4 -> t2.A0,A1 ; P7 -> t3.B0,B1 ; P8 -> t3.A0,A1.
// Waits: vmcnt(8) at P4 (retires t3_{prev}) and P8 (retires t2).
// Issue->consume distance: 4-5 phases => HBM latency covered.
template<int MODE>
__global__ __launch_bounds__(512, 2)
void gemm8(const u16* __restrict__ A,
           const u16* __restrict__ Bq, const u16* __restrict__ Bk, const u16* __restrict__ Bv,
           const float* __restrict__ biasq, const float* __restrict__ biask, const float* __restrict__ biasvv,
           const float* __restrict__ res, float* __restrict__ outF,
           u16* __restrict__ outBq, u16* __restrict__ outBk, u16* __restrict__ outBv,
           int M, int N, int K)
{
    __shared__ u16 lds[2][4][8192];   // [buf][A0,A1,B0,B1][128x64] = 128 KB
    const int tid = threadIdx.x, lane = tid & 63, w = tid >> 6;
    const int lr = lane & 15, lg = lane >> 4;
    const int wm = w >> 2, wn = w & 3;          // 2 x 4 wave grid

    const u16* Bm = Bq; const float* bias = biasq; u16* outB = outBq;
    float scl = 1.0f; int nt = blockIdx.x;
    if (MODE == 0) {
        int mat = nt >> 2; nt &= 3;
        if (mat == 1)      { Bm = Bk; bias = biask; outB = outBk; }
        else if (mat == 2) { Bm = Bv; bias = biasvv; outB = outBv; }
        if (mat == 0) scl = 0.125f;             // D^-0.5
    }
    const int m0 = blockIdx.y * 256, n0 = nt * 256;
    const int NI = K >> 7;                      // 2 K-tiles (of 64) per iter

    // staging: dest byte p -> logical (row,col) via inverse swizzle
    const int p    = w * 1024 + lane * 16;
    const int lby  = p ^ (((p >> 7) & 7) << 4);
    const int srow = lby >> 7;            // 0..63 (sub-stage adds 64)
    const int scol = (lby & 127) >> 1;    // element col, 8-aligned

    auto STAGE = [&](int buf, int half, const u16* src, int grow0, int rowmax, int t) {
#pragma unroll
        for (int s = 0; s < 2; ++s) {
            int gr = grow0 + s * 64 + srow; if (gr > rowmax) gr = rowmax;
            gload16(src + (size_t)gr * K + (t << 6) + scol,
                    (char*)&lds[buf][half][0] + s * 8192 + w * 1024);
        }
    };
    auto LDA = [&](int buf, int mh, int mf, int kh) -> s16x8 {
        const char* b = (const char*)&lds[buf][wm][0];
        int inrow = mh * 64 + mf * 16 + lr;
        return *(const s16x8*)(b + inrow * 128 + ((kh * 64 + lg * 16) ^ ((lr & 7) << 4)));
    };
    auto LDB = [&](int buf, int nh, int nf, int kh) -> s16x8 {
        const char* b = (const char*)&lds[buf][2 + (wn >> 1)][0];
        int inrow = (wn & 1) * 64 + nh * 32 + nf * 16 + lr;
        return *(const s16x8*)(b + inrow * 128 + ((kh * 64 + lg * 16) ^ ((lr & 7) << 4)));
    };

    f32x4 acc[8][4];
#pragma unroll
    for (int i = 0; i < 8; ++i)
#pragma unroll
        for (int j = 0; j < 4; ++j) { f32x4 z = {0.f, 0.f, 0.f, 0.f}; acc[i][j] = z; }

    s16x8 a[4][2], b[2][2][2];
    auto MFQ = [&](int mh, int nh) {
        __builtin_amdgcn_s_setprio(1);
#pragma unroll
        for (int mf = 0; mf < 4; ++mf)
#pragma unroll
            for (int nf = 0; nf < 2; ++nf)
#pragma unroll
                for (int kh = 0; kh < 2; ++kh)
                    acc[mh * 4 + mf][nh * 2 + nf] =
                        MFMA16(a[mf][kh], b[nh][nf][kh], acc[mh * 4 + mf][nh * 2 + nf]);
        __builtin_amdgcn_s_setprio(0);
    };

    // ---- prologue: stage t0 and t1 fully (16 loads); wait t0 (vmcnt 8) ----
    STAGE(0, 0, A,  m0,       M - 1, 0);
    STAGE(0, 1, A,  m0 + 128, M - 1, 0);
    STAGE(0, 2, Bm, n0,       N - 1, 0);
    STAGE(0, 3, Bm, n0 + 128, N - 1, 0);
    STAGE(1, 0, A,  m0,       M - 1, 1);
    STAGE(1, 1, A,  m0 + 128, M - 1, 1);
    STAGE(1, 2, Bm, n0,       N - 1, 1);
    STAGE(1, 3, Bm, n0 + 128, N - 1, 1);
    VMC8;
    BAR();

    for (int i = 0; i < NI; ++i) {
        const int t2 = 2 * i + 2, t3 = 2 * i + 3;
        const bool more = (i + 1 < NI);
        // ---- P1: tile t0 quad(0,0) ----
#pragma unroll
        for (int mf = 0; mf < 4; ++mf)
#pragma unroll
            for (int kh = 0; kh < 2; ++kh) a[mf][kh] = LDA(0, 0, mf, kh);
#pragma unroll
        for (int nf = 0; nf < 2; ++nf)
#pragma unroll
            for (int kh = 0; kh < 2; ++kh) b[0][nf][kh] = LDB(0, 0, nf, kh);
        BAR(); LGKM0;
        MFQ(0, 0);
        BAR();
        // ---- P2: quad(0,1) ----
#pragma unroll
        for (int nf = 0; nf < 2; ++nf)
#pragma unroll
            for (int kh = 0; kh < 2; ++kh) b[1][nf][kh] = LDB(0, 1, nf, kh);
        BAR(); LGKM0;
        MFQ(0, 1);
        BAR();
        // ---- P3: quad(1,1); stage t2.B0,B1 (buf0 B last read in P2) ----
#pragma unroll
        for (int mf = 0; mf < 4; ++mf)
#pragma unroll
            for (int kh = 0; kh < 2; ++kh) a[mf][kh] = LDA(0, 1, mf, kh);
        if (more) {
            STAGE(0, 2, Bm, n0,       N - 1, t2);
            STAGE(0, 3, Bm, n0 + 128, N - 1, t2);
        }
        BAR(); LGKM0;
        MFQ(1, 1);
        BAR();
        // ---- P4: quad(1,0); stage t2.A0,A1; wait t1-ready for P5 ----
        if (more) {
            STAGE(0, 0, A, m0,       M - 1, t2);
            STAGE(0, 1, A, m0 + 128, M - 1, t2);
        }
        MFQ(1, 0);
        if (more) { VMC8; } else { VMC0; }
        BAR();
        // ---- P5: tile t1 quad(0,0) ----
#pragma unroll
        for (int mf = 0; mf < 4; ++mf)
#pragma unroll
            for (int kh = 0; kh < 2; ++kh) a[mf][kh] = LDA(1, 0, mf, kh);
#pragma unroll
        for (int nf = 0; nf < 2; ++nf)
#pragma unroll
            for (int kh = 0; kh < 2; ++kh) b[0][nf][kh] = LDB(1, 0, nf, kh);
        BAR(); LGKM0;
        MFQ(0, 0);
        BAR();
        // ---- P6: quad(0,1) ----
#pragma unroll
        for (int nf = 0; nf < 2; ++nf)
#pragma unroll
            for (int kh = 0; kh < 2; ++kh) b[1][nf][kh] = LDB(1, 1, nf, kh);
        BAR(); LGKM0;
        MFQ(0, 1);
        BAR();
        // ---- P7: quad(1,1); stage t3.B0,B1 ----
#pragma unroll
        for (int mf = 0; mf < 4; ++mf)
#pragma unroll
            for (int kh = 0; kh < 2; ++kh) a[mf][kh] = LDA(1, 1, mf, kh);
        if (more) {
            STAGE(1, 2, Bm, n0,       N - 1, t3);
            STAGE(1, 3, Bm, n0 + 128, N - 1, t3);
        }
        BAR(); LGKM0;
        MFQ(1, 1);
        BAR();
        // ---- P8: quad(1,0); stage t3.A0,A1; wait t2-ready for next P1 ----
        if (more) {
            STAGE(1, 0, A, m0,       M - 1, t3);
            STAGE(1, 1, A, m0 + 128, M - 1, t3);
            MFQ(1, 0);
            VMC8;
        } else {
            MFQ(1, 0);
        }
        BAR();
    }

    // ---- epilogue ----
    float biasv[4];
#pragma unroll
    for (int an = 0; an < 4; ++an)
        biasv[an] = bias[n0 + wn * 64 + (an >> 1) * 32 + (an & 1) * 16 + lr];

#pragma unroll
    for (int am = 0; am < 8; ++am) {
#pragma unroll
        for (int r = 0; r < 4; ++r) {
            int row = m0 + wm * 128 + (am >> 2) * 64 + (am & 3) * 16 + lg * 4 + r;
            if (row >= M) continue;
            if (MODE == 0) {
                int bb = row / S_;
                int ss = row - bb * S_;
#pragma unroll
                for (int an = 0; an < 4; ++an) {
                    int col = n0 + wn * 64 + (an >> 1) * 32 + (an & 1) * 16 + lr;
                    int hh = col >> 6, dd = col & 63;
                    float v = (acc[am][an][r] + biasv[an]) * scl;
                    outB[(((size_t)bb * H_ + hh) * S_ + ss) * D_ + dd] = f2bf(v);
                }
            } else if (MODE == 1) {
                size_t base = (size_t)row * N;
#pragma unroll
                for (int an = 0; an < 4; ++an) {
                    int col = n0 + wn * 64 + (an >> 1) * 32 + (an & 1) * 16 + lr;
                    outF[base + col] = acc[am][an][r] + biasv[an] + res[base + col];
                }
            } else {
                size_t base = (size_t)row * N;
#pragma unroll
                for (int an = 0; an < 4; ++an) {
                    int col = n0 + wn * 64 + (an >> 1) * 32 + (an & 1) * 16 + lr;
                    float x = acc[am][an][r] + biasv[an];
                    float u2 = 1.5957691216057308f * (x + 0.044715f * x * x * x);
                    u2 = fminf(u2, 80.0f);
                    float t = __expf(u2);          // gelu = x * t / (1 + t)
                    outB[base + col] = f2bf(x * t / (1.0f + t));
                }
            }
        }
    }
}

// ---------------- fused attention: one WG per (b,h) ----------------
__global__ __launch_bounds__(256)
void attn_kernel(const u16* __restrict__ qg_, const u16* __restrict__ kg_,
                 const u16* __restrict__ vg_, const u16* __restrict__ msum,
                 u16* __restrict__ ctx)
{
    __shared__ u16 Ks[272 * 72];
    __shared__ u16 Vt[64 * 296];
    __shared__ u16 Ps[4][16 * 32];
    const int bh = blockIdx.x;
    const int b = bh >> 4, hh = bh & 15;
    const u16* kg = kg_ + (size_t)bh * (S_ * D_);
    const u16* vg = vg_ + (size_t)bh * (S_ * D_);
    const u16* qg = qg_ + (size_t)bh * (S_ * D_);
    const int tid = threadIdx.x, lane = tid & 63, wv = tid >> 6;

    for (int c = tid; c < (S_ * D_) / 8; c += 256) {
        int s = c >> 3, d8 = (c & 7) << 3;
        s16x8 val = *(const s16x8*)(kg + s * 64 + d8);
        *(s16x8*)&Ks[s * 72 + d8] = val;
    }
    for (int idx = tid; idx < 15 * 64; idx += 256) {
        int rr = 257 + (idx >> 6), cc = idx & 63;
        Ks[rr * 72 + cc] = 0;
    }
    for (int c = tid; c < (S_ * D_) / 8; c += 256) {
        int s = c >> 3, d8 = (c & 7) << 3;
        s16x8 val = *(const s16x8*)(vg + s * 64 + d8);
#pragma unroll
        for (int j = 0; j < 8; ++j) Vt[(d8 + j) * 296 + s] = (u16)val[j];
    }
    for (int idx = tid; idx < 64 * 39; idx += 256) {
        int dd = idx / 39, cc = 257 + idx % 39;
        Vt[dd * 296 + cc] = 0;
    }
    __syncthreads();

    const int lr = lane & 15, lg = lane >> 4;
    for (int qb = wv; qb < 17; qb += 4) {
        const int q0 = qb * 16;
        int qrow = q0 + lr; if (qrow > S_ - 1) qrow = S_ - 1;
        s16x8 aq0 = *(const s16x8*)(qg + qrow * 64 + lg * 8);
        s16x8 aq1 = *(const s16x8*)(qg + qrow * 64 + 32 + lg * 8);

        f32x4 sc[17];
#pragma unroll
        for (int t = 0; t < 17; ++t) { f32x4 z = {0.f, 0.f, 0.f, 0.f}; sc[t] = z; }
#pragma unroll
        for (int t = 0; t < 17; ++t) {
            s16x8 b0 = *(const s16x8*)&Ks[(t * 16 + lr) * 72 + lg * 8];
            s16x8 b1 = *(const s16x8*)&Ks[(t * 16 + lr) * 72 + 32 + lg * 8];
            sc[t] = MFMA16(aq0, b0, sc[t]);
            sc[t] = MFMA16(aq1, b1, sc[t]);
        }
        float mx[4] = {-3e38f, -3e38f, -3e38f, -3e38f};
#pragma unroll
        for (int r = 0; r < 4; ++r) {
            int sq = q0 + lg * 4 + r; if (sq > S_ - 1) sq = S_ - 1;
            const u16* mrow = msum + ((size_t)b * S_ + sq) * 272;
#pragma unroll
            for (int t = 0; t < 17; ++t) {
                sc[t][r] += bf2f(mrow[t * 16 + lr]);
                mx[r] = fmaxf(mx[r], sc[t][r]);
            }
        }
#pragma unroll
        for (int r = 0; r < 4; ++r) {
#pragma unroll
            for (int xm = 1; xm <= 8; xm <<= 1)
                mx[r] = fmaxf(mx[r], __shfl_xor(mx[r], xm, 64));
        }
        float sum[4] = {0.f, 0.f, 0.f, 0.f};
#pragma unroll
        for (int t = 0; t < 17; ++t)
#pragma unroll
            for (int r = 0; r < 4; ++r) {
                float e = __expf(sc[t][r] - mx[r]);
                sc[t][r] = e; sum[r] += e;
            }
#pragma unroll
        for (int r = 0; r < 4; ++r) {
#pragma unroll
            for (int xm = 1; xm <= 8; xm <<= 1)
                sum[r] += __shfl_xor(sum[r], xm, 64);
        }

        f32x4 ac[4];
#pragma unroll
        for (int nt = 0; nt < 4; ++nt) { f32x4 z = {0.f, 0.f, 0.f, 0.f}; ac[nt] = z; }
        u16* myP = &Ps[wv][0];
#pragma unroll
        for (int kc = 0; kc < 9; ++kc) {
#pragma unroll
            for (int tt = 0; tt < 2; ++tt) {
                const int t = kc * 2 + tt;
#pragma unroll
                for (int r = 0; r < 4; ++r) {
                    float pv = (t < 17) ? sc[(t < 17) ? t : 0][r] : 0.f;
                    myP[(lg * 4 + r) * 32 + tt * 16 + lr] = f2bf(pv);
                }
            }
            s16x8 pa = *(const s16x8*)&myP[lr * 32 + lg * 8];
#pragma unroll
            for (int nt = 0; nt < 4; ++nt) {
                s16x8 bv = *(const s16x8*)&Vt[(nt * 16 + lr) * 296 + kc * 32 + lg * 8];
                ac[nt] = MFMA16(pa, bv, ac[nt]);
            }
        }
#pragma unroll
        for (int r = 0; r < 4; ++r) {
            int sq = q0 + lg * 4 + r;
            if (sq < S_) {
                float rd = 1.0f / sum[r];
                size_t base = (((size_t)b * S_ + sq) * H_ + hh) * D_;
#pragma unroll
                for (int nt = 0; nt < 4; ++nt)
                    ctx[base + nt * 16 + lr] = f2bf(ac[nt][r] * rd);
            }
        }
    }
}

// ---------------- launch ----------------
extern "C" void kernel_launch(void* const* d_in, const int* in_sizes, int n_in,
                              void* d_out, int out_size, void* d_ws, size_t ws_size,
                              hipStream_t stream)
{
    const float* hid   = (const float*)d_in[0];
    const float* am    = (const float*)d_in[1];
    const float* cm    = (const float*)d_in[2];
    const float* ln1w  = (const float*)d_in[3];
    const float* ln1b  = (const float*)d_in[4];
    const float* qw    = (const float*)d_in[5];
    const float* qbias = (const float*)d_in[6];
    const float* kw    = (const float*)d_in[7];
    const float* kbias = (const float*)d_in[8];
    const float* vw    = (const float*)d_in[9];
    const float* vbias = (const float*)d_in[10];
    const float* ow    = (const float*)d_in[11];
    const float* obias = (const float*)d_in[12];
    const float* ln2w  = (const float*)d_in[13];
    const float* ln2b  = (const float*)d_in[14];
    const float* f1w   = (const float*)d_in[15];
    const float* f1b   = (const float*)d_in[16];
    const float* f2w   = (const float*)d_in[17];
    const float* f2b   = (const float*)d_in[18];
    float* out = (float*)d_out;

    const size_t ME = (size_t)M_ * E_;
    u16* Wq   = (u16*)d_ws;
    u16* Wk   = Wq + 1048576;
    u16* Wv   = Wk + 1048576;
    u16* Wo   = Wv + 1048576;
    u16* Wf1  = Wo + 1048576;
    u16* Wf2  = Wf1 + 4 * 1048576;
    u16* xln  = Wf2 + 4 * 1048576;
    u16* qb_  = xln + ME;
    u16* kb_  = qb_ + ME;
    u16* vb_  = kb_ + ME;
    u16* ctx  = vb_ + ME;
    float* hbuf = (float*)(ctx + ME);
    u16* msum = (u16*)(hbuf + ME);
    u16* act  = qb_;      // reuse q..ctx region = M x I bf16 (exact fit)
    u16* x2   = xln;

    convert_w_kernel<<<3072, 256, 0, stream>>>(qw, kw, vw, ow, f1w, f2w, Wq);
    mask_combine_kernel<<<8736, 256, 0, stream>>>(am, cm, msum);
    ln_kernel<<<M_, 256, 0, stream>>>(hid, ln1w, ln1b, xln);
    gemm8<0><<<dim3(12, 33), 512, 0, stream>>>(xln, Wq, Wk, Wv, qbias, kbias, vbias,
                                               nullptr, nullptr, qb_, kb_, vb_,
                                               M_, 1024, 1024);
    attn_kernel<<<512, 256, 0, stream>>>(qb_, kb_, vb_, msum, ctx);
    gemm8<1><<<dim3(4, 33), 512, 0, stream>>>(ctx, Wo, nullptr, nullptr, obias, nullptr, nullptr,
                                              hid, hbuf, nullptr, nullptr, nullptr,
                                              M_, 1024, 1024);
    ln_kernel<<<M_, 256, 0, stream>>>(hbuf, ln2w, ln2b, x2);
    gemm8<2><<<dim3(16, 33), 512, 0, stream>>>(x2, Wf1, nullptr, nullptr, f1b, nullptr, nullptr,
                                               nullptr, nullptr, act, nullptr, nullptr,
                                               M_, 4096, 1024);
    gemm8<1><<<dim3(4, 33), 512, 0, stream>>>(act, Wf2, nullptr, nullptr, f2b, nullptr, nullptr,
                                              hbuf, out, nullptr, nullptr, nullptr,
                                              M_, 1024, 4096);
}